// Round 3
// baseline (623.224 us; speedup 1.0000x reference)
//
#include <hip/hip_runtime.h>
#include <math.h>

#define BB 8
#define TT 4096
#define DDIM 512
#define KK 4096
#define NN (BB*TT)
#define EPS 0.05f

typedef __attribute__((ext_vector_type(8))) short bf16x8;
typedef __attribute__((ext_vector_type(4))) float f32x4;

__device__ __forceinline__ void async16(void* lds, const void* g) {
  __builtin_amdgcn_global_load_lds((const __attribute__((address_space(1))) void*)g,
                                   (__attribute__((address_space(3))) void*)lds, 16, 0, 0);
}

__device__ __forceinline__ unsigned pk_bf16(float a, float b) {
  unsigned ua = __float_as_uint(a); ua += 0x7FFFu + ((ua >> 16) & 1u);
  unsigned ub = __float_as_uint(b); ub += 0x7FFFu + ((ub >> 16) & 1u);
  return (ua >> 16) | (ub & 0xFFFF0000u);
}

// ---------- prep: row sum-sq (esq or inv2=2/norm) + bf16 (RTNE) conversion ----------
__global__ __launch_bounds__(256) void prep_kernel(const float* __restrict__ src,
                                                   short* __restrict__ dst16,
                                                   float* __restrict__ outv, int mode) {
  int r = blockIdx.x * 4 + (threadIdx.x >> 6);
  int lane = threadIdx.x & 63;
  const float4* row4 = (const float4*)(src + (size_t)r * DDIM);
  float4 v0 = row4[lane];
  float4 v1 = row4[lane + 64];
  uint2 p0, p1;
  p0.x = pk_bf16(v0.x, v0.y); p0.y = pk_bf16(v0.z, v0.w);
  p1.x = pk_bf16(v1.x, v1.y); p1.y = pk_bf16(v1.z, v1.w);
  *(uint2*)(dst16 + (size_t)r * DDIM + lane * 4) = p0;
  *(uint2*)(dst16 + (size_t)r * DDIM + 256 + lane * 4) = p1;
  float ss = v0.x*v0.x + v0.y*v0.y + v0.z*v0.z + v0.w*v0.w
           + v1.x*v1.x + v1.y*v1.y + v1.z*v1.z + v1.w*v1.w;
  #pragma unroll
  for (int off = 32; off; off >>= 1) ss += __shfl_down(ss, off);
  if (lane == 0) outv[r] = mode ? 2.0f / fmaxf(sqrtf(ss), 1e-12f) : ss;
}

// ---------- main MFMA pass: A-resident in LDS, B streamed L2->registers ----------
// 256 blocks (1/CU), 512 threads (8 waves = 2 row-halves x 4 code-quarters).
// A (128 rows x 512 dims bf16, 128 KiB) staged ONCE into LDS (XOR-swizzled).
// B fragments are loaded DIRECTLY from the bf16 codebook in global memory
// (L2-resident, proven by round-2's FETCH_SIZE=33MB) — no B LDS staging, and
// therefore NO barriers in the main loop. Waves free-run; the compiler hoists
// next-step loads above current MFMAs; no vmcnt(0)/lgkmcnt(0) drains anywhere.
// Each block scans all 4096 codes; per-row top-2 kept in registers.
__global__ __launch_bounds__(512, 2) void vq_mfma(const short* __restrict__ xb,
                                                  const short* __restrict__ eb,
                                                  const float* __restrict__ esq,
                                                  const float* __restrict__ inv2,
                                                  float* __restrict__ out_ind,
                                                  int* __restrict__ flags,
                                                  int* __restrict__ list,
                                                  int* __restrict__ cnt) {
  __shared__ __attribute__((aligned(16))) short As[128 * 512];   // 131072 B
  __shared__ float rS1[4][128];
  __shared__ float rS2[4][128];
  __shared__ int   rI1[4][128];

  const int tid = threadIdx.x;
  const int lane = tid & 63;
  const int w = tid >> 6;          // 0..7
  const int wr = w >> 2;           // row half (0..1): rows wr*64..+64
  const int wc = w & 3;            // code quarter within each 256-code tile
  const int q = lane >> 4, c16 = lane & 15;
  const int n0 = blockIdx.x * 128;

  // ---- A stage (once): LDS row j*8+w; physical 16B-chunk `lane` holds global
  // chunk lane^w (per-row XOR swizzle: logical chunk c at physical c ^ (row&7))
  #pragma unroll
  for (int j = 0; j < 16; ++j)
    async16(As + (j * 8 + w) * 512,
            xb + (size_t)(n0 + j * 8 + w) * 512 + (lane ^ w) * 8);

  const int arow0 = (wr * 64 + c16) * 512;   // + ti*8192 + ach (shorts)

  // B global fragment base for this thread: code component (wc*64 + c16),
  // k-chunk q (8 consecutive dims = 16B). Full addr adds ct*256*512 +
  // tj*16*512 + s*32 (shorts).
  const short* gB = eb + (size_t)(wc * 64 + c16) * DDIM + q * 8;

  // inv2 values for my 16 row-slots (regs for whole kernel)
  f32x4 iv4[4];
  #pragma unroll
  for (int ti = 0; ti < 4; ++ti)
    iv4[ti] = *(const f32x4*)&inv2[n0 + wr * 64 + ti * 16 + q * 4];

  float s1[16], s2v[16];
  int   i1[16];
  #pragma unroll
  for (int s = 0; s < 16; ++s) { s1[s] = -3e38f; s2v[s] = -3e38f; i1[s] = 0; }

  __syncthreads();   // A landed (vmcnt(0) drain happens once, here only)

  for (int ct = 0; ct < 16; ++ct) {
    const short* gBc = gB + (size_t)ct * 256 * DDIM;
    float nes[4];
    #pragma unroll
    for (int tj = 0; tj < 4; ++tj)
      nes[tj] = -esq[ct * 256 + wc * 64 + tj * 16 + c16];
    f32x4 acc[4][4];
    #pragma unroll
    for (int ti = 0; ti < 4; ++ti)
      #pragma unroll
      for (int tj = 0; tj < 4; ++tj) acc[ti][tj] = (f32x4){0.f, 0.f, 0.f, 0.f};

    #pragma unroll
    for (int s = 0; s < 16; ++s) {
      bf16x8 af[4], bf[4];
      #pragma unroll
      for (int tj = 0; tj < 4; ++tj)
        bf[tj] = *(const bf16x8*)(gBc + (size_t)tj * 16 * DDIM + s * 32);
      const int ach = ((s * 4 + q) ^ (c16 & 7)) * 8;
      #pragma unroll
      for (int ti = 0; ti < 4; ++ti)
        af[ti] = *(const bf16x8*)(As + arow0 + ti * 8192 + ach);
      __builtin_amdgcn_s_setprio(1);
      #pragma unroll
      for (int ti = 0; ti < 4; ++ti)
        #pragma unroll
        for (int tj = 0; tj < 4; ++tj)
          acc[ti][tj] = __builtin_amdgcn_mfma_f32_16x16x32_bf16(af[ti], bf[tj], acc[ti][tj], 0, 0, 0);
      __builtin_amdgcn_s_setprio(0);
    }

    // ---------- epilogue for this 256-code tile (registers only) ----------
    const int colbase = ct * 256 + wc * 64 + c16;
    #pragma unroll
    for (int ti = 0; ti < 4; ++ti)
      #pragma unroll
      for (int r = 0; r < 4; ++r) {
        const int slot = ti * 4 + r;
        const float iv = iv4[ti][r];
        #pragma unroll
        for (int tj = 0; tj < 4; ++tj) {
          float sc = fmaf(acc[ti][tj][r], iv, nes[tj]);
          float mn = fminf(sc, s1[slot]);
          s2v[slot] = fmaxf(s2v[slot], mn);
          if (sc > s1[slot]) { s1[slot] = sc; i1[slot] = colbase + tj * 16; }
        }
      }
  }

  // ---------- final merge: 16 lanes -> 4 wc-waves -> write results ----------
  #pragma unroll
  for (int slot = 0; slot < 16; ++slot) {
    float a1 = s1[slot], a2 = s2v[slot]; int ai = i1[slot];
    #pragma unroll
    for (int off = 1; off < 16; off <<= 1) {
      float b1 = __shfl_xor(a1, off);
      float b2 = __shfl_xor(a2, off);
      int   bi = __shfl_xor(ai, off);
      float mn = fminf(a1, b1);
      a2 = fmaxf(fmaxf(a2, b2), mn);
      if (b1 > a1 || (b1 == a1 && bi < ai)) { a1 = b1; ai = bi; }
    }
    if (c16 == 0) {
      int row = wr * 64 + (slot >> 2) * 16 + q * 4 + (slot & 3);
      rS1[wc][row] = a1; rS2[wc][row] = a2; rI1[wc][row] = ai;
    }
  }
  __syncthreads();
  if (tid < 128) {
    float a1 = rS1[0][tid], a2 = rS2[0][tid]; int ai = rI1[0][tid];
    #pragma unroll
    for (int gq = 1; gq < 4; ++gq) {
      float b1 = rS1[gq][tid], b2 = rS2[gq][tid]; int bi = rI1[gq][tid];
      float mn = fminf(a1, b1);
      a2 = fmaxf(fmaxf(a2, b2), mn);
      if (b1 > a1 || (b1 == a1 && bi < ai)) { a1 = b1; ai = bi; }
    }
    const int row = n0 + tid;
    out_ind[row] = (float)ai;
    if (a1 - a2 < EPS) {
      int p = atomicAdd(cnt, 1);
      list[p] = row;
      flags[row] = p + 1;
    } else {
      flags[row] = 0;
    }
  }
}

// ---------- cleanup: exact fp32 rescore of flagged rows (split 8 k-chunks) ----------
__global__ __launch_bounds__(256) void cleanup_kernel(const float* __restrict__ x,
                                                      const float* __restrict__ embed,
                                                      const float* __restrict__ esq,
                                                      const float* __restrict__ inv2,
                                                      const int* __restrict__ list,
                                                      const int* __restrict__ cnt,
                                                      float2* __restrict__ exact) {
  __shared__ float xr[DDIM];
  __shared__ float red_s[4];
  __shared__ int   red_i[4];
  const int rs = blockIdx.x & 31, kc = blockIdx.x >> 5;
  const int tid = threadIdx.x;
  const int lane = tid & 63, wid = tid >> 6;
  const int n = *cnt;
  for (int ii = rs; ii < n; ii += 32) {
    const int row = list[ii];
    __syncthreads();
    if (tid < 128) *(float4*)&xr[tid * 4] = *(const float4*)&x[(size_t)row * DDIM + tid * 4];
    __syncthreads();
    const float iv = inv2[row];
    float bs = -3e38f; int bi = 0;
    for (int cc = 0; cc < 2; ++cc) {
      const int code = kc * 512 + cc * 256 + tid;
      const float4* er = (const float4*)&embed[(size_t)code * DDIM];
      float acc = 0.f;
      for (int d = 0; d < DDIM / 4; ++d) {
        float4 e4 = er[d];
        float4 x4 = *(const float4*)&xr[d * 4];
        acc += x4.x * e4.x + x4.y * e4.y + x4.z * e4.z + x4.w * e4.w;
      }
      float sc = fmaf(acc, iv, -esq[code]);
      if (sc > bs || (sc == bs && code < bi)) { bs = sc; bi = code; }
    }
    #pragma unroll
    for (int off = 1; off < 64; off <<= 1) {
      float b1 = __shfl_xor(bs, off);
      int   b2 = __shfl_xor(bi, off);
      if (b1 > bs || (b1 == bs && b2 < bi)) { bs = b1; bi = b2; }
    }
    if (lane == 0) { red_s[wid] = bs; red_i[wid] = bi; }
    __syncthreads();
    if (tid == 0) {
      for (int ww = 1; ww < 4; ++ww)
        if (red_s[ww] > red_s[0] || (red_s[ww] == red_s[0] && red_i[ww] < red_i[0])) {
          red_s[0] = red_s[ww]; red_i[0] = red_i[ww];
        }
      exact[(size_t)ii * 8 + kc] = make_float2(red_s[0], (float)red_i[0]);
    }
  }
}

// ---------- gather + transpose (merges exact results for flagged rows) ----------
__global__ __launch_bounds__(256) void gather_kernel(const float* __restrict__ embed,
                                                     const int* __restrict__ flags,
                                                     const float2* __restrict__ exact,
                                                     float* __restrict__ out_ind,
                                                     float* __restrict__ out_q) {
  __shared__ int lidx[64];
  __shared__ float trans[64 * 65];
  const int n0 = blockIdx.x * 64;
  const int tid = threadIdx.x;
  if (tid < 64) {
    const int row = n0 + tid;
    const int f = flags[row];
    int idx;
    if (f) {
      float bsv = -3e38f; int bi = 0;
      const float2* e8 = &exact[(size_t)(f - 1) * 8];
      #pragma unroll
      for (int k = 0; k < 8; ++k) {
        float2 t = e8[k];
        int ci = (int)t.y;
        if (t.x > bsv || (t.x == bsv && ci < bi)) { bsv = t.x; bi = ci; }
      }
      idx = bi;
      out_ind[row] = (float)idx;
    } else {
      idx = (int)out_ind[row];
    }
    lidx[tid] = idx;
  }
  __syncthreads();
  const int bb = n0 >> 12;
  const int t0 = n0 & (TT - 1);
  const int w = tid >> 6, lane = tid & 63;
  for (int d0 = 0; d0 < DDIM; d0 += 64) {
    if (d0) __syncthreads();
    #pragma unroll
    for (int qq = 0; qq < 16; ++qq) {
      int tt2 = w * 16 + qq;
      int e = lidx[tt2];
      trans[lane * 65 + tt2] = embed[(size_t)e * DDIM + d0 + lane];
    }
    __syncthreads();
    #pragma unroll
    for (int qq = 0; qq < 4; ++qq) {
      int dl = (tid >> 4) * 4 + qq;
      int t4 = (tid & 15) * 4;
      float4 o;
      o.x = trans[dl * 65 + t4 + 0];
      o.y = trans[dl * 65 + t4 + 1];
      o.z = trans[dl * 65 + t4 + 2];
      o.w = trans[dl * 65 + t4 + 3];
      *(float4*)&out_q[((size_t)bb * DDIM + d0 + dl) * TT + t0 + t4] = o;
    }
  }
}

extern "C" void kernel_launch(void* const* d_in, const int* in_sizes, int n_in,
                              void* d_out, int out_size, void* d_ws, size_t ws_size,
                              hipStream_t stream) {
  const float* x     = (const float*)d_in[0];
  const float* embed = (const float*)d_in[1];
  char* ws = (char*)d_ws;
  short* xb      = (short*)(ws);                         // 33,554,432 B
  short* eb      = (short*)(ws + 33554432);              //  4,194,304 B
  float* esq     = (float*)(ws + 37748736);              //     16,384 B
  float* inv2    = (float*)(ws + 37765120);              //    131,072 B
  int* list      = (int*)(ws + 39993344);                //    131,072 B
  int* flags     = (int*)(ws + 40124416);                //    131,072 B
  float2* exact  = (float2*)(ws + 40255488);             //  2,097,152 B
  int* cnt       = (int*)(ws + 42352640);                //          4 B

  float* out_ind = (float*)d_out;
  float* out_q   = out_ind + NN;

  prep_kernel<<<KK / 4, 256, 0, stream>>>(embed, eb, esq, 0);
  prep_kernel<<<NN / 4, 256, 0, stream>>>(x, xb, inv2, 1);
  hipMemsetAsync(cnt, 0, 4, stream);
  vq_mfma<<<256, 512, 0, stream>>>(xb, eb, esq, inv2, out_ind, flags, list, cnt);
  cleanup_kernel<<<256, 256, 0, stream>>>(x, embed, esq, inv2, list, cnt, exact);
  gather_kernel<<<NN / 64, 256, 0, stream>>>(embed, flags, exact, out_ind, out_q);
}

// Round 4
// 414.030 us; speedup vs baseline: 1.5053x; 1.5053x over previous
//
#include <hip/hip_runtime.h>
#include <math.h>

#define BB 8
#define TT 4096
#define DDIM 512
#define KK 4096
#define NN (BB*TT)
#define EPS 0.05f

typedef __attribute__((ext_vector_type(8))) short bf16x8;
typedef __attribute__((ext_vector_type(4))) float f32x4;

__device__ __forceinline__ void async16(void* lds, const void* g) {
  __builtin_amdgcn_global_load_lds((const __attribute__((address_space(1))) void*)g,
                                   (__attribute__((address_space(3))) void*)lds, 16, 0, 0);
}

__device__ __forceinline__ unsigned pk_bf16(float a, float b) {
  unsigned ua = __float_as_uint(a); ua += 0x7FFFu + ((ua >> 16) & 1u);
  unsigned ub = __float_as_uint(b); ub += 0x7FFFu + ((ub >> 16) & 1u);
  return (ua >> 16) | (ub & 0xFFFF0000u);
}

// ---------- prep: row sum-sq (esq or inv2=2/norm) + bf16 (RTNE) conversion ----------
__global__ __launch_bounds__(256) void prep_kernel(const float* __restrict__ src,
                                                   short* __restrict__ dst16,
                                                   float* __restrict__ outv, int mode) {
  int r = blockIdx.x * 4 + (threadIdx.x >> 6);
  int lane = threadIdx.x & 63;
  const float4* row4 = (const float4*)(src + (size_t)r * DDIM);
  float4 v0 = row4[lane];
  float4 v1 = row4[lane + 64];
  uint2 p0, p1;
  p0.x = pk_bf16(v0.x, v0.y); p0.y = pk_bf16(v0.z, v0.w);
  p1.x = pk_bf16(v1.x, v1.y); p1.y = pk_bf16(v1.z, v1.w);
  *(uint2*)(dst16 + (size_t)r * DDIM + lane * 4) = p0;
  *(uint2*)(dst16 + (size_t)r * DDIM + 256 + lane * 4) = p1;
  float ss = v0.x*v0.x + v0.y*v0.y + v0.z*v0.z + v0.w*v0.w
           + v1.x*v1.x + v1.y*v1.y + v1.z*v1.z + v1.w*v1.w;
  #pragma unroll
  for (int off = 32; off; off >>= 1) ss += __shfl_down(ss, off);
  if (lane == 0) outv[r] = mode ? 2.0f / fmaxf(sqrtf(ss), 1e-12f) : ss;
}

// ---------- main MFMA pass: A-resident in LDS, B streamed L2->registers, PACED ----------
// 256 blocks (1/CU), 512 threads (8 waves = 2 row-halves x 4 code-quarters).
// A (128 rows x 512 dims bf16, 128 KiB) staged ONCE into LDS (XOR-swizzled).
// B fragments load DIRECTLY from the bf16 codebook (global/L2) into registers,
// software-pipelined one step ahead so each load has a full MFMA phase of cover.
// ONE raw s_barrier per 256-code tile (no waitcnt drain - pure pacing): keeps
// the block's waves, and hence all 256 blocks, scanning the same B window so
// L2 serves ~all codebook traffic (round-3 ran barrier-free and thrashed:
// FETCH 805 MB; round-2's per-step barriers gave FETCH 33 MB).
__global__ __launch_bounds__(512, 2) void vq_mfma(const short* __restrict__ xb,
                                                  const short* __restrict__ eb,
                                                  const float* __restrict__ esq,
                                                  const float* __restrict__ inv2,
                                                  float* __restrict__ out_ind,
                                                  int* __restrict__ flags,
                                                  int* __restrict__ list,
                                                  int* __restrict__ cnt) {
  __shared__ __attribute__((aligned(16))) short As[128 * 512];   // 131072 B
  __shared__ float rS1[4][128];
  __shared__ float rS2[4][128];
  __shared__ int   rI1[4][128];

  const int tid = threadIdx.x;
  const int lane = tid & 63;
  const int w = tid >> 6;          // 0..7
  const int wr = w >> 2;           // row half (0..1): rows wr*64..+64
  const int wc = w & 3;            // code quarter within each 256-code tile
  const int q = lane >> 4, c16 = lane & 15;
  const int n0 = blockIdx.x * 128;

  // ---- A stage (once): LDS row j*8+w; physical 16B-chunk `lane` holds global
  // chunk lane^w (per-row XOR swizzle: logical chunk c at physical c ^ (row&7))
  #pragma unroll
  for (int j = 0; j < 16; ++j)
    async16(As + (j * 8 + w) * 512,
            xb + (size_t)(n0 + j * 8 + w) * 512 + (lane ^ w) * 8);

  const int arow0 = (wr * 64 + c16) * 512;   // + ti*8192 + ach (shorts)

  // B global fragment base: code (col) = wc*64 + c16, k-chunk = q (8 dims, 16B).
  // Full addr adds ct*256*512 + tj*16*512 + s*32 (shorts).
  const short* gB = eb + (size_t)(wc * 64 + c16) * DDIM + q * 8;

  // inv2 values for my 16 row-slots (regs for whole kernel)
  f32x4 iv4[4];
  #pragma unroll
  for (int ti = 0; ti < 4; ++ti)
    iv4[ti] = *(const f32x4*)&inv2[n0 + wr * 64 + ti * 16 + q * 4];

  float s1[16], s2v[16];
  int   i1[16];
  #pragma unroll
  for (int s = 0; s < 16; ++s) { s1[s] = -3e38f; s2v[s] = -3e38f; i1[s] = 0; }

  // prefetch B fragments for (ct=0, s=0) before waiting on A
  bf16x8 bfc[4];
  #pragma unroll
  for (int tj = 0; tj < 4; ++tj)
    bfc[tj] = *(const bf16x8*)(gB + (size_t)tj * 16 * DDIM);

  __syncthreads();   // A landed (vmcnt(0) drain happens once, here only)

  for (int ct = 0; ct < 16; ++ct) {
    const short* gBc = gB + (size_t)ct * 256 * DDIM;
    // uniform base for the cross-ct prefetch (clamped at the last tile)
    const short* gBn_ct = (ct < 15) ? gBc + 256 * DDIM : gBc;
    float nes[4];
    #pragma unroll
    for (int tj = 0; tj < 4; ++tj)
      nes[tj] = -esq[ct * 256 + wc * 64 + tj * 16 + c16];
    f32x4 acc[4][4];
    #pragma unroll
    for (int ti = 0; ti < 4; ++ti)
      #pragma unroll
      for (int tj = 0; tj < 4; ++tj) acc[ti][tj] = (f32x4){0.f, 0.f, 0.f, 0.f};

    #pragma unroll
    for (int s = 0; s < 16; ++s) {
      // issue next step's B loads first (longest latency, covered by MFMAs)
      bf16x8 bfn[4];
      const short* gBn = (s < 15) ? (gBc + (s + 1) * 32) : gBn_ct;
      #pragma unroll
      for (int tj = 0; tj < 4; ++tj)
        bfn[tj] = *(const bf16x8*)(gBn + (size_t)tj * 16 * DDIM);
      // A fragments from LDS (swizzled)
      const int ach = ((s * 4 + q) ^ (c16 & 7)) * 8;
      bf16x8 af[4];
      #pragma unroll
      for (int ti = 0; ti < 4; ++ti)
        af[ti] = *(const bf16x8*)(As + arow0 + ti * 8192 + ach);
      __builtin_amdgcn_s_setprio(1);
      #pragma unroll
      for (int ti = 0; ti < 4; ++ti)
        #pragma unroll
        for (int tj = 0; tj < 4; ++tj)
          acc[ti][tj] = __builtin_amdgcn_mfma_f32_16x16x32_bf16(af[ti], bfc[tj], acc[ti][tj], 0, 0, 0);
      __builtin_amdgcn_s_setprio(0);
      #pragma unroll
      for (int tj = 0; tj < 4; ++tj) bfc[tj] = bfn[tj];
    }

    // ---------- epilogue for this 256-code tile (registers only) ----------
    // (also covers the latency of the already-issued next-ct B prefetch)
    const int colbase = ct * 256 + wc * 64 + c16;
    #pragma unroll
    for (int ti = 0; ti < 4; ++ti)
      #pragma unroll
      for (int r = 0; r < 4; ++r) {
        const int slot = ti * 4 + r;
        const float iv = iv4[ti][r];
        #pragma unroll
        for (int tj = 0; tj < 4; ++tj) {
          float sc = fmaf(acc[ti][tj][r], iv, nes[tj]);
          float mn = fminf(sc, s1[slot]);
          s2v[slot] = fmaxf(s2v[slot], mn);
          if (sc > s1[slot]) { s1[slot] = sc; i1[slot] = colbase + tj * 16; }
        }
      }

    // pacing barrier: raw s_barrier, NO waitcnt drain (A read-only, B in regs).
    // Keeps all waves/blocks on the same codebook window -> L2 hits.
    __builtin_amdgcn_s_barrier();
  }

  // ---------- final merge: 16 lanes -> 4 wc-waves -> write results ----------
  #pragma unroll
  for (int slot = 0; slot < 16; ++slot) {
    float a1 = s1[slot], a2 = s2v[slot]; int ai = i1[slot];
    #pragma unroll
    for (int off = 1; off < 16; off <<= 1) {
      float b1 = __shfl_xor(a1, off);
      float b2 = __shfl_xor(a2, off);
      int   bi = __shfl_xor(ai, off);
      float mn = fminf(a1, b1);
      a2 = fmaxf(fmaxf(a2, b2), mn);
      if (b1 > a1 || (b1 == a1 && bi < ai)) { a1 = b1; ai = bi; }
    }
    if (c16 == 0) {
      int row = wr * 64 + (slot >> 2) * 16 + q * 4 + (slot & 3);
      rS1[wc][row] = a1; rS2[wc][row] = a2; rI1[wc][row] = ai;
    }
  }
  __syncthreads();
  if (tid < 128) {
    float a1 = rS1[0][tid], a2 = rS2[0][tid]; int ai = rI1[0][tid];
    #pragma unroll
    for (int gq = 1; gq < 4; ++gq) {
      float b1 = rS1[gq][tid], b2 = rS2[gq][tid]; int bi = rI1[gq][tid];
      float mn = fminf(a1, b1);
      a2 = fmaxf(fmaxf(a2, b2), mn);
      if (b1 > a1 || (b1 == a1 && bi < ai)) { a1 = b1; ai = bi; }
    }
    const int row = n0 + tid;
    out_ind[row] = (float)ai;
    if (a1 - a2 < EPS) {
      int p = atomicAdd(cnt, 1);
      list[p] = row;
      flags[row] = p + 1;
    } else {
      flags[row] = 0;
    }
  }
}

// ---------- cleanup: exact fp32 rescore of flagged rows (split 8 k-chunks) ----------
__global__ __launch_bounds__(256) void cleanup_kernel(const float* __restrict__ x,
                                                      const float* __restrict__ embed,
                                                      const float* __restrict__ esq,
                                                      const float* __restrict__ inv2,
                                                      const int* __restrict__ list,
                                                      const int* __restrict__ cnt,
                                                      float2* __restrict__ exact) {
  __shared__ float xr[DDIM];
  __shared__ float red_s[4];
  __shared__ int   red_i[4];
  const int rs = blockIdx.x & 31, kc = blockIdx.x >> 5;
  const int tid = threadIdx.x;
  const int lane = tid & 63, wid = tid >> 6;
  const int n = *cnt;
  for (int ii = rs; ii < n; ii += 32) {
    const int row = list[ii];
    __syncthreads();
    if (tid < 128) *(float4*)&xr[tid * 4] = *(const float4*)&x[(size_t)row * DDIM + tid * 4];
    __syncthreads();
    const float iv = inv2[row];
    float bs = -3e38f; int bi = 0;
    for (int cc = 0; cc < 2; ++cc) {
      const int code = kc * 512 + cc * 256 + tid;
      const float4* er = (const float4*)&embed[(size_t)code * DDIM];
      float acc = 0.f;
      for (int d = 0; d < DDIM / 4; ++d) {
        float4 e4 = er[d];
        float4 x4 = *(const float4*)&xr[d * 4];
        acc += x4.x * e4.x + x4.y * e4.y + x4.z * e4.z + x4.w * e4.w;
      }
      float sc = fmaf(acc, iv, -esq[code]);
      if (sc > bs || (sc == bs && code < bi)) { bs = sc; bi = code; }
    }
    #pragma unroll
    for (int off = 1; off < 64; off <<= 1) {
      float b1 = __shfl_xor(bs, off);
      int   b2 = __shfl_xor(bi, off);
      if (b1 > bs || (b1 == bs && b2 < bi)) { bs = b1; bi = b2; }
    }
    if (lane == 0) { red_s[wid] = bs; red_i[wid] = bi; }
    __syncthreads();
    if (tid == 0) {
      for (int ww = 1; ww < 4; ++ww)
        if (red_s[ww] > red_s[0] || (red_s[ww] == red_s[0] && red_i[ww] < red_i[0])) {
          red_s[0] = red_s[ww]; red_i[0] = red_i[ww];
        }
      exact[(size_t)ii * 8 + kc] = make_float2(red_s[0], (float)red_i[0]);
    }
  }
}

// ---------- gather + transpose (merges exact results for flagged rows) ----------
__global__ __launch_bounds__(256) void gather_kernel(const float* __restrict__ embed,
                                                     const int* __restrict__ flags,
                                                     const float2* __restrict__ exact,
                                                     float* __restrict__ out_ind,
                                                     float* __restrict__ out_q) {
  __shared__ int lidx[64];
  __shared__ float trans[64 * 65];
  const int n0 = blockIdx.x * 64;
  const int tid = threadIdx.x;
  if (tid < 64) {
    const int row = n0 + tid;
    const int f = flags[row];
    int idx;
    if (f) {
      float bsv = -3e38f; int bi = 0;
      const float2* e8 = &exact[(size_t)(f - 1) * 8];
      #pragma unroll
      for (int k = 0; k < 8; ++k) {
        float2 t = e8[k];
        int ci = (int)t.y;
        if (t.x > bsv || (t.x == bsv && ci < bi)) { bsv = t.x; bi = ci; }
      }
      idx = bi;
      out_ind[row] = (float)idx;
    } else {
      idx = (int)out_ind[row];
    }
    lidx[tid] = idx;
  }
  __syncthreads();
  const int bb = n0 >> 12;
  const int t0 = n0 & (TT - 1);
  const int w = tid >> 6, lane = tid & 63;
  for (int d0 = 0; d0 < DDIM; d0 += 64) {
    if (d0) __syncthreads();
    #pragma unroll
    for (int qq = 0; qq < 16; ++qq) {
      int tt2 = w * 16 + qq;
      int e = lidx[tt2];
      trans[lane * 65 + tt2] = embed[(size_t)e * DDIM + d0 + lane];
    }
    __syncthreads();
    #pragma unroll
    for (int qq = 0; qq < 4; ++qq) {
      int dl = (tid >> 4) * 4 + qq;
      int t4 = (tid & 15) * 4;
      float4 o;
      o.x = trans[dl * 65 + t4 + 0];
      o.y = trans[dl * 65 + t4 + 1];
      o.z = trans[dl * 65 + t4 + 2];
      o.w = trans[dl * 65 + t4 + 3];
      *(float4*)&out_q[((size_t)bb * DDIM + d0 + dl) * TT + t0 + t4] = o;
    }
  }
}

extern "C" void kernel_launch(void* const* d_in, const int* in_sizes, int n_in,
                              void* d_out, int out_size, void* d_ws, size_t ws_size,
                              hipStream_t stream) {
  const float* x     = (const float*)d_in[0];
  const float* embed = (const float*)d_in[1];
  char* ws = (char*)d_ws;
  short* xb      = (short*)(ws);                         // 33,554,432 B
  short* eb      = (short*)(ws + 33554432);              //  4,194,304 B
  float* esq     = (float*)(ws + 37748736);              //     16,384 B
  float* inv2    = (float*)(ws + 37765120);              //    131,072 B
  int* list      = (int*)(ws + 39993344);                //    131,072 B
  int* flags     = (int*)(ws + 40124416);                //    131,072 B
  float2* exact  = (float2*)(ws + 40255488);             //  2,097,152 B
  int* cnt       = (int*)(ws + 42352640);                //          4 B

  float* out_ind = (float*)d_out;
  float* out_q   = out_ind + NN;

  prep_kernel<<<KK / 4, 256, 0, stream>>>(embed, eb, esq, 0);
  prep_kernel<<<NN / 4, 256, 0, stream>>>(x, xb, inv2, 1);
  hipMemsetAsync(cnt, 0, 4, stream);
  vq_mfma<<<256, 512, 0, stream>>>(xb, eb, esq, inv2, out_ind, flags, list, cnt);
  cleanup_kernel<<<256, 256, 0, stream>>>(x, embed, esq, inv2, list, cnt, exact);
  gather_kernel<<<NN / 64, 256, 0, stream>>>(embed, flags, exact, out_ind, out_q);
}